// Round 8
// baseline (257.940 us; speedup 1.0000x reference)
//
#include <hip/hip_runtime.h>
#include <cmath>

typedef unsigned long long u64;
typedef __attribute__((ext_vector_type(2))) unsigned long long u64x2;

constexpr int      kLevels   = 12;
constexpr unsigned kHashSize = 1u << 19;            // 524288 entries/level
constexpr unsigned kHashMask = kHashSize - 1u;
constexpr int      kPoints   = 1 << 21;             // 2,097,152
constexpr int      kHalf     = kPoints / 2;         // 1,048,576
constexpr int      kBlock    = 256;

constexpr int kLowLevels = 3;                       // gathered in assemble (L2-hit)
constexpr int kHiLevels  = kLevels - kLowLevels;    // 9: phased gather

// ---- gather geometry (per half) ----
constexpr int kILP       = 16;
constexpr int kPtsPerBlk = kBlock * kILP;           // 4096
constexpr int kChunksH   = kHalf / kPtsPerBlk;      // 256 chunks/level/half
constexpr int kGBlocksH  = kHiLevels * kChunksH;    // 2304
constexpr int kXcds      = 8;
constexpr int kQLenH     = kGBlocksH / kXcds;       // 288 (exact)

// ---- assemble geometry (per half) ----
constexpr int kABlocksH  = kHalf / kBlock;          // 4096

// ---- mix-launch geometry: interleave 8 gather + 8 assemble blocks ----
constexpr int kInterleaved = 2 * kGBlocksH;                   // 4608
constexpr int kMixBlocks   = kInterleaved + (kABlocksH - kGBlocksH); // 6400

struct ResArr { float r[kLevels]; };

// ---------------- gather family: XCD-pinned, level-phased, inline hash ----
// MSHR-bound (~0.26 lanes/cy/CU, rounds 4-7); x reads/hash VALU hide under it.
__device__ __forceinline__ void gather_work(
    unsigned g, unsigned half_base,
    const float* __restrict__ x, const u64* __restrict__ emb,
    u64* __restrict__ ws, const ResArr& res)
{
    const unsigned gq    = (g % (unsigned)kXcds) * (unsigned)kQLenH
                         + (g / (unsigned)kXcds);           // level-major/XCD
    const unsigned li    = gq / (unsigned)kChunksH;         // 0..8
    const unsigned chunk = gq - li * (unsigned)kChunksH;
    const unsigned level = li + (unsigned)kLowLevels;

    float r = res.r[kLowLevels];
#pragma unroll
    for (int i = 1; i < kHiLevels; ++i)
        r = (li == (unsigned)i) ? res.r[kLowLevels + i] : r;

    const u64* __restrict__ tab = emb + (size_t)level * kHashSize;
    u64*       __restrict__ wsl = ws  + (size_t)li * kPoints;
    const unsigned base = half_base + chunk * (unsigned)kPtsPerBlk + threadIdx.x;

    unsigned h[kILP];
#pragma unroll
    for (int k = 0; k < kILP; ++k) {
        const unsigned p = base + (unsigned)(k * kBlock);
        const float px = x[p * 3u + 0u];
        const float py = x[p * 3u + 1u];
        const float pz = x[p * 3u + 2u];
        h[k] = ((unsigned)floorf(px * r)
              ^ ((unsigned)floorf(py * r) * 2654435761u)
              ^ ((unsigned)floorf(pz * r) * 805459861u)) & kHashMask;
    }

    u64 e[kILP];
#pragma unroll
    for (int k = 0; k < kILP; ++k)
        e[k] = tab[h[k]];

    asm volatile("" ::                      // keep 16 results live; no refusion
        "v"(e[0]),  "v"(e[1]),  "v"(e[2]),  "v"(e[3]),
        "v"(e[4]),  "v"(e[5]),  "v"(e[6]),  "v"(e[7]),
        "v"(e[8]),  "v"(e[9]),  "v"(e[10]), "v"(e[11]),
        "v"(e[12]), "v"(e[13]), "v"(e[14]), "v"(e[15]));

#pragma unroll
    for (int k = 0; k < kILP; ++k)
        __builtin_nontemporal_store(e[k], wsl + base + (unsigned)(k * kBlock));
}

// ---------------- assemble family: low-level gather + ws read + LDS pack --
// Every global store is 64 lanes x 16 B contiguous (full lines).
__device__ __forceinline__ void assemble_work(
    unsigned pbase,
    const float* __restrict__ x, const u64* __restrict__ emb,
    const u64* __restrict__ ws, u64x2* __restrict__ out,
    const ResArr& res, u64 (*lds)[kLevels + 1])
{
    const unsigned t = threadIdx.x;
    const unsigned p = pbase + t;

    const float px = x[p * 3u + 0u];
    const float py = x[p * 3u + 1u];
    const float pz = x[p * 3u + 2u];

#pragma unroll
    for (int l = 0; l < kLowLevels; ++l) {          // small tables: L2 hits
        const float r = res.r[l];
        const unsigned x0 = (unsigned)floorf(px * r);
        const unsigned y0 = (unsigned)floorf(py * r);
        const unsigned z0 = (unsigned)floorf(pz * r);
        const unsigned h  = (x0 ^ (y0 * 2654435761u) ^ (z0 * 805459861u)) & kHashMask;
        lds[t][l] = emb[(size_t)l * kHashSize + h];
    }
#pragma unroll
    for (int li = 0; li < kHiLevels; ++li) {        // coalesced 512 B/instr
        lds[t][kLowLevels + li] =
            __builtin_nontemporal_load(ws + (size_t)li * kPoints + p);
    }
    __syncthreads();

#pragma unroll
    for (int j = 0; j < 6; ++j) {
        const unsigned el = (unsigned)(j * kBlock) + t;   // 0..1535
        const unsigned p2 = el / 6u;
        const unsigned s2 = el - p2 * 6u;
        u64x2 o;
        o.x = lds[p2][2u * s2 + 0u];
        o.y = lds[p2][2u * s2 + 1u];
        __builtin_nontemporal_store(o, out + (size_t)pbase * 6u + el);
    }
}

// ---------------- Launch 1: gather(A) --------------------------------------
__global__ __launch_bounds__(kBlock) void gather_a_kernel(
    const float* __restrict__ x, const u64* __restrict__ emb,
    u64* __restrict__ ws, ResArr res)
{
    gather_work(blockIdx.x, 0u, x, emb, ws, res);
}

// ---------------- Launch 2: gather(B) || assemble(A) -----------------------
// Interleave in groups of 8 so the gather family's g %8 == blockIdx %8
// (preserves XCD pinning); assemble blocks fill the other 8-groups + tail.
__global__ __launch_bounds__(kBlock) void mix_kernel(
    const float* __restrict__ x, const u64* __restrict__ emb,
    u64* __restrict__ ws, u64x2* __restrict__ out, ResArr res)
{
    __shared__ u64 lds[kBlock][kLevels + 1];        // 26.7 KB (all blocks)
    const unsigned bid = blockIdx.x;
    if (bid < (unsigned)kInterleaved) {
        const unsigned grp  = bid >> 4;
        const unsigned slot = bid & 15u;
        if (slot < 8u) {
            const unsigned g = grp * 8u + slot;     // g % 8 == bid % 8
            gather_work(g, (unsigned)kHalf, x, emb, ws, res);
        } else {
            const unsigned a = grp * 8u + (slot - 8u);      // 0..2303
            assemble_work(a * (unsigned)kBlock, x, emb, ws, out, res, lds);
        }
    } else {
        const unsigned a = (unsigned)kGBlocksH + (bid - (unsigned)kInterleaved);
        assemble_work(a * (unsigned)kBlock, x, emb, ws, out, res, lds);
    }
}

// ---------------- Launch 3: assemble(B) ------------------------------------
__global__ __launch_bounds__(kBlock) void assemble_b_kernel(
    const float* __restrict__ x, const u64* __restrict__ emb,
    const u64* __restrict__ ws, u64x2* __restrict__ out, ResArr res)
{
    __shared__ u64 lds[kBlock][kLevels + 1];
    assemble_work((unsigned)kHalf + blockIdx.x * (unsigned)kBlock,
                  x, emb, ws, out, res, lds);
}

// ---------------- Fallback: round-1 direct kernel (if ws too small) -------
__global__ __launch_bounds__(kBlock) void direct_kernel(
    const float* __restrict__ x,
    const u64*   __restrict__ emb,
    u64*         __restrict__ out,
    ResArr res)
{
    unsigned tid = blockIdx.x * (unsigned)kBlock + threadIdx.x;  // n*12 + l
    unsigned n   = tid / (unsigned)kLevels;
    unsigned l   = tid - n * (unsigned)kLevels;
    float r = res.r[0];
#pragma unroll
    for (int i = 1; i < kLevels; ++i) r = (l == (unsigned)i) ? res.r[i] : r;
    float px = x[n * 3u], py = x[n * 3u + 1u], pz = x[n * 3u + 2u];
    unsigned x0 = (unsigned)floorf(px * r);
    unsigned y0 = (unsigned)floorf(py * r);
    unsigned z0 = (unsigned)floorf(pz * r);
    unsigned h  = (x0 ^ (y0 * 2654435761u) ^ (z0 * 805459861u)) & kHashMask;
    __builtin_nontemporal_store(emb[l * kHashSize + h], out + tid);
}

extern "C" void kernel_launch(void* const* d_in, const int* in_sizes, int n_in,
                              void* d_out, int out_size, void* d_ws, size_t ws_size,
                              hipStream_t stream) {
    const float* x   = (const float*)d_in[0];
    const u64*   emb = (const u64*)d_in[1];

    // Replicate the reference's float64 resolution computation exactly.
    ResArr res;
    const double growth = std::exp((std::log(512.0) - std::log(16.0)) / 11.0);
    for (int i = 0; i < kLevels; ++i)
        res.r[i] = (float)(int)(16.0 * std::pow(growth, (double)i));

    const size_t ws_needed = (size_t)kHiLevels * kPoints * sizeof(u64); // 151 MB

    if (ws_size >= ws_needed) {
        hipLaunchKernelGGL(gather_a_kernel, dim3(kGBlocksH), dim3(kBlock), 0, stream,
                           x, emb, (u64*)d_ws, res);
        hipLaunchKernelGGL(mix_kernel, dim3(kMixBlocks), dim3(kBlock), 0, stream,
                           x, emb, (u64*)d_ws, (u64x2*)d_out, res);
        hipLaunchKernelGGL(assemble_b_kernel, dim3(kABlocksH), dim3(kBlock), 0, stream,
                           x, emb, (const u64*)d_ws, (u64x2*)d_out, res);
    } else {
        const int total = kPoints * kLevels;
        hipLaunchKernelGGL(direct_kernel, dim3(total / kBlock), dim3(kBlock), 0, stream,
                           x, emb, (u64*)d_out, res);
    }
}

// Round 9
// 235.986 us; speedup vs baseline: 1.0930x; 1.0930x over previous
//
#include <hip/hip_runtime.h>
#include <cmath>

typedef unsigned long long u64;
typedef __attribute__((ext_vector_type(2))) unsigned long long u64x2;

constexpr int      kLevels   = 12;
constexpr unsigned kHashSize = 1u << 19;            // 524288 entries/level
constexpr unsigned kHashMask = kHashSize - 1u;
constexpr int      kPoints   = 1 << 21;             // 2,097,152
constexpr int      kBlock    = 256;

// Levels 0..2 (gather-line footprint ~2.5 MB total < 4 MB L2): gathered
// inline in the assemble pass on every XCD. Levels 3..11 (~2.7-4 MB each):
// XCD-pinned, level-phased gather so each XCD's L2 holds one active table.
constexpr int kLowLevels = 3;
constexpr int kHiLevels  = kLevels - kLowLevels;    // 9

// ---- gather geometry ----
constexpr int kILP       = 16;                      // gathers in flight/wave
constexpr int kPtsPerBlk = kBlock * kILP;           // 4096
constexpr int kChunks    = kPoints / kPtsPerBlk;    // 512 chunks/level
constexpr int kGBlocks   = kHiLevels * kChunks;     // 4608
constexpr int kXcds      = 8;
constexpr int kQLen      = kGBlocks / kXcds;        // 576 (exact)

struct ResArr { float r[kLevels]; };

// ---------- Pass 1: XCD-pinned, level-phased gather, inline hash ----------
// blockIdx % 8 picks the XCD (round-robin dispatch); each XCD walks a
// level-major queue so it gathers from one table at a time (L2-resident).
// Inline hash (no idx round-trip): x re-reads are cheap L1/L2 hits and the
// hash VALU hides under the line-request-bound gather stream.
__global__ __launch_bounds__(kBlock) void gather_hi_kernel(
    const float* __restrict__ x,     // [N,3]
    const u64*   __restrict__ emb,   // [L * 2^19] float2 as u64
    u64*         __restrict__ ws,    // [9][N]
    ResArr res)
{
    const unsigned b     = blockIdx.x;
    const unsigned g     = (b % (unsigned)kXcds) * (unsigned)kQLen
                         + (b / (unsigned)kXcds);
    const unsigned li    = g / (unsigned)kChunks;           // 0..8
    const unsigned chunk = g - li * (unsigned)kChunks;
    const unsigned level = li + (unsigned)kLowLevels;

    float r = res.r[kLowLevels];
#pragma unroll
    for (int i = 1; i < kHiLevels; ++i)
        r = (li == (unsigned)i) ? res.r[kLowLevels + i] : r;

    const u64*    __restrict__ tab = emb + (size_t)level * kHashSize;
    u64*          __restrict__ wsl = ws  + (size_t)li * kPoints;
    const float3* __restrict__ x3  = (const float3*)x;
    const unsigned base = chunk * (unsigned)kPtsPerBlk + threadIdx.x;

    unsigned h[kILP];
#pragma unroll
    for (int k = 0; k < kILP; ++k) {
        const float3 pp = x3[base + (unsigned)(k * kBlock)];  // one 12B load
        h[k] = ((unsigned)floorf(pp.x * r)
              ^ ((unsigned)floorf(pp.y * r) * 2654435761u)
              ^ ((unsigned)floorf(pp.z * r) * 805459861u)) & kHashMask;
    }

    u64 e[kILP];
#pragma unroll
    for (int k = 0; k < kILP; ++k)      // 16 independent L2-resident gathers
        e[k] = tab[h[k]];

    // Keep all 16 results simultaneously live so regalloc cannot re-fuse
    // load->store pairs (round-6-verified: VGPR=32, true 16-deep MLP).
    asm volatile("" ::
        "v"(e[0]),  "v"(e[1]),  "v"(e[2]),  "v"(e[3]),
        "v"(e[4]),  "v"(e[5]),  "v"(e[6]),  "v"(e[7]),
        "v"(e[8]),  "v"(e[9]),  "v"(e[10]), "v"(e[11]),
        "v"(e[12]), "v"(e[13]), "v"(e[14]), "v"(e[15]));

#pragma unroll
    for (int k = 0; k < kILP; ++k)      // coalesced 512 B/instr stream
        __builtin_nontemporal_store(e[k], wsl + base + (unsigned)(k * kBlock));
}

// ---------- Pass 2: gather levels 0..2 + read ws + LDS-staged assembly ----
// Every global store is 64 lanes x 16 B contiguous (full 64-B lines,
// write amplification = 1; round-2's 2.9x disaster fixed by this pack).
__global__ __launch_bounds__(kBlock) void assemble_kernel(
    const float* __restrict__ x,
    const u64*   __restrict__ emb,
    const u64*   __restrict__ ws,
    u64x2*       __restrict__ out,   // [N*6] of 16 B  (== [N,24] f32)
    ResArr res)
{
    __shared__ u64 lds[kBlock][kLevels + 1];       // [256][13] u64, +1 pad
    const unsigned t    = threadIdx.x;
    const unsigned base = blockIdx.x * (unsigned)kBlock;
    const unsigned p    = base + t;

    const float3 pp = ((const float3*)x)[p];

#pragma unroll
    for (int l = 0; l < kLowLevels; ++l) {         // small tables: L2 hits
        const float r = res.r[l];
        const unsigned x0 = (unsigned)floorf(pp.x * r);
        const unsigned y0 = (unsigned)floorf(pp.y * r);
        const unsigned z0 = (unsigned)floorf(pp.z * r);
        const unsigned h  = (x0 ^ (y0 * 2654435761u) ^ (z0 * 805459861u)) & kHashMask;
        lds[t][l] = emb[(size_t)l * kHashSize + h];
    }
#pragma unroll
    for (int li = 0; li < kHiLevels; ++li) {       // coalesced 512 B/instr
        lds[t][kLowLevels + li] =
            __builtin_nontemporal_load(ws + (size_t)li * kPoints + p);
    }
    __syncthreads();

#pragma unroll
    for (int j = 0; j < 6; ++j) {
        const unsigned el = (unsigned)(j * kBlock) + t;   // 0..1535
        const unsigned p2 = el / 6u;
        const unsigned s2 = el - p2 * 6u;
        u64x2 o;
        o.x = lds[p2][2u * s2 + 0u];
        o.y = lds[p2][2u * s2 + 1u];
        __builtin_nontemporal_store(o, out + (size_t)base * 6u + el);
    }
}

// ---------- Fallback: round-1 direct kernel (if ws too small) -------------
__global__ __launch_bounds__(kBlock) void direct_kernel(
    const float* __restrict__ x,
    const u64*   __restrict__ emb,
    u64*         __restrict__ out,
    ResArr res)
{
    unsigned tid = blockIdx.x * (unsigned)kBlock + threadIdx.x;  // n*12 + l
    unsigned n   = tid / (unsigned)kLevels;
    unsigned l   = tid - n * (unsigned)kLevels;
    float r = res.r[0];
#pragma unroll
    for (int i = 1; i < kLevels; ++i) r = (l == (unsigned)i) ? res.r[i] : r;
    float px = x[n * 3u], py = x[n * 3u + 1u], pz = x[n * 3u + 2u];
    unsigned x0 = (unsigned)floorf(px * r);
    unsigned y0 = (unsigned)floorf(py * r);
    unsigned z0 = (unsigned)floorf(pz * r);
    unsigned h  = (x0 ^ (y0 * 2654435761u) ^ (z0 * 805459861u)) & kHashMask;
    __builtin_nontemporal_store(emb[l * kHashSize + h], out + tid);
}

extern "C" void kernel_launch(void* const* d_in, const int* in_sizes, int n_in,
                              void* d_out, int out_size, void* d_ws, size_t ws_size,
                              hipStream_t stream) {
    const float* x   = (const float*)d_in[0];
    const u64*   emb = (const u64*)d_in[1];

    // Replicate the reference's float64 resolution computation exactly.
    ResArr res;
    const double growth = std::exp((std::log(512.0) - std::log(16.0)) / 11.0);
    for (int i = 0; i < kLevels; ++i)
        res.r[i] = (float)(int)(16.0 * std::pow(growth, (double)i));

    const size_t ws_needed = (size_t)kHiLevels * kPoints * sizeof(u64); // 151 MB

    if (ws_size >= ws_needed) {
        hipLaunchKernelGGL(gather_hi_kernel, dim3(kGBlocks), dim3(kBlock), 0, stream,
                           x, emb, (u64*)d_ws, res);
        hipLaunchKernelGGL(assemble_kernel, dim3(kPoints / kBlock), dim3(kBlock), 0, stream,
                           x, emb, (const u64*)d_ws, (u64x2*)d_out, res);
    } else {
        const int total = kPoints * kLevels;
        hipLaunchKernelGGL(direct_kernel, dim3(total / kBlock), dim3(kBlock), 0, stream,
                           x, emb, (u64*)d_out, res);
    }
}

// Round 10
// 223.790 us; speedup vs baseline: 1.1526x; 1.0545x over previous
//
#include <hip/hip_runtime.h>
#include <cmath>

typedef unsigned long long u64;
typedef __attribute__((ext_vector_type(2))) unsigned long long u64x2;

constexpr int      kLevels   = 12;
constexpr unsigned kHashSize = 1u << 19;            // 524288 entries/level
constexpr unsigned kHashMask = kHashSize - 1u;
constexpr int      kPoints   = 1 << 21;             // 2,097,152
constexpr int      kBlock    = 256;

// Levels 0..2 (gather-line footprint ~2.2 MB < 4 MB L2): gathered inline in
// the assemble pass on every XCD. Levels 3..11 (~2.7-4 MB each): hash
// precomputed (pass 0), then XCD-pinned level-phased gather (pass 1) so each
// XCD's private 4 MB L2 holds the one active table.
constexpr int kLowLevels = 3;
constexpr int kHiLevels  = kLevels - kLowLevels;    // 9

// ---- pass-0 geometry ----
constexpr int kHILP       = 4;
constexpr int kHashBlocks = kPoints / (kBlock * kHILP);   // 2048

// ---- pass-1 geometry ----
constexpr int kILP       = 16;                      // gathers in flight/wave
constexpr int kPtsPerBlk = kBlock * kILP;           // 4096
constexpr int kChunks    = kPoints / kPtsPerBlk;    // 512 chunks/level
constexpr int kGBlocks   = kHiLevels * kChunks;     // 4608
constexpr int kXcds      = 8;
constexpr int kQLen      = kGBlocks / kXcds;        // 576 (exact)

struct ResArr { float r[kLevels]; };

// ---------- Pass 0: read x ONCE, write hi-level hash indices -> d_out -----
// idx lives in d_out (75 MB of its 201 MB), dead until assemble overwrites it.
// (Measured 17 us; separating hash from gather is what lets the gather's asm
// liveness barrier actually hold — round 9 proved inlining collapses MLP.)
__global__ __launch_bounds__(kBlock) void hash_kernel(
    const float* __restrict__ x,     // [N,3]
    unsigned*    __restrict__ idx,   // [9][N] u32
    ResArr res)
{
    const unsigned base = blockIdx.x * (unsigned)(kBlock * kHILP) + threadIdx.x;
#pragma unroll
    for (int k = 0; k < kHILP; ++k) {
        const unsigned p = base + (unsigned)(k * kBlock);
        const float px = x[p * 3u + 0u];
        const float py = x[p * 3u + 1u];
        const float pz = x[p * 3u + 2u];
#pragma unroll
        for (int li = 0; li < kHiLevels; ++li) {
            const float r = res.r[kLowLevels + li];
            const unsigned x0 = (unsigned)floorf(px * r);
            const unsigned y0 = (unsigned)floorf(py * r);
            const unsigned z0 = (unsigned)floorf(pz * r);
            const unsigned h  = (x0 ^ (y0 * 2654435761u) ^ (z0 * 805459861u)) & kHashMask;
            __builtin_nontemporal_store(h, idx + (size_t)li * kPoints + p);
        }
    }
}

// ---------- Pass 1: XCD-pinned, level-phased, MLP-held gather -------------
// blockIdx % 8 picks the XCD (round-robin dispatch); each XCD walks a
// level-major queue so its L2 holds one active table. The asm barrier keeps
// all 16 gather results live (round-6-verified VGPR=32 -> true 16-deep MLP).
// Plain loads for the table (L2 retention wanted; r7 proved bypass hurts).
__global__ __launch_bounds__(kBlock) void gather_hi_kernel(
    const unsigned* __restrict__ idx,   // [9][N]
    const u64*      __restrict__ emb,   // [L * 2^19] float2 as u64
    u64*            __restrict__ ws)    // [9][N]
{
    const unsigned b     = blockIdx.x;
    const unsigned g     = (b % (unsigned)kXcds) * (unsigned)kQLen
                         + (b / (unsigned)kXcds);
    const unsigned li    = g / (unsigned)kChunks;           // 0..8
    const unsigned chunk = g - li * (unsigned)kChunks;
    const unsigned level = li + (unsigned)kLowLevels;

    const u64*      __restrict__ tab  = emb + (size_t)level * kHashSize;
    const unsigned* __restrict__ idxl = idx + (size_t)li * kPoints;
    u64*            __restrict__ wsl  = ws  + (size_t)li * kPoints;
    const unsigned base = chunk * (unsigned)kPtsPerBlk + threadIdx.x;

    unsigned h[kILP];
#pragma unroll
    for (int k = 0; k < kILP; ++k)
        h[k] = __builtin_nontemporal_load(idxl + base + (unsigned)(k * kBlock));

    u64 e[kILP];
#pragma unroll
    for (int k = 0; k < kILP; ++k)      // 16 independent L2-resident gathers
        e[k] = tab[h[k]];

    // Force all 16 results simultaneously live; stores cannot hoist above.
    asm volatile("" ::
        "v"(e[0]),  "v"(e[1]),  "v"(e[2]),  "v"(e[3]),
        "v"(e[4]),  "v"(e[5]),  "v"(e[6]),  "v"(e[7]),
        "v"(e[8]),  "v"(e[9]),  "v"(e[10]), "v"(e[11]),
        "v"(e[12]), "v"(e[13]), "v"(e[14]), "v"(e[15]));

#pragma unroll
    for (int k = 0; k < kILP; ++k)      // coalesced 512 B/instr stream
        __builtin_nontemporal_store(e[k], wsl + base + (unsigned)(k * kBlock));
}

// ---------- Pass 2: gather levels 0..2 + read ws + LDS-staged assembly ----
// 1 point/thread (measured faster than the 2-pt variant). Every global store
// is 64 lanes x 16 B contiguous -> full 64-B lines, write amplification = 1.
__global__ __launch_bounds__(kBlock) void assemble_kernel(
    const float* __restrict__ x,
    const u64*   __restrict__ emb,
    const u64*   __restrict__ ws,
    u64x2*       __restrict__ out,   // [N*6] of 16 B  (== [N,24] f32)
    ResArr res)
{
    __shared__ u64 lds[kBlock][kLevels + 1];       // [256][13] u64, +1 pad
    const unsigned t    = threadIdx.x;
    const unsigned base = blockIdx.x * (unsigned)kBlock;
    const unsigned p    = base + t;

    const float px = x[p * 3u + 0u];
    const float py = x[p * 3u + 1u];
    const float pz = x[p * 3u + 2u];

#pragma unroll
    for (int l = 0; l < kLowLevels; ++l) {         // small tables: L2 hits
        const float r = res.r[l];
        const unsigned x0 = (unsigned)floorf(px * r);
        const unsigned y0 = (unsigned)floorf(py * r);
        const unsigned z0 = (unsigned)floorf(pz * r);
        const unsigned h  = (x0 ^ (y0 * 2654435761u) ^ (z0 * 805459861u)) & kHashMask;
        lds[t][l] = emb[(size_t)l * kHashSize + h];
    }
#pragma unroll
    for (int li = 0; li < kHiLevels; ++li) {       // coalesced 512 B/instr
        lds[t][kLowLevels + li] =
            __builtin_nontemporal_load(ws + (size_t)li * kPoints + p);
    }
    __syncthreads();

#pragma unroll
    for (int j = 0; j < 6; ++j) {
        const unsigned el = (unsigned)(j * kBlock) + t;   // 0..1535
        const unsigned p2 = el / 6u;
        const unsigned s2 = el - p2 * 6u;
        u64x2 o;
        o.x = lds[p2][2u * s2 + 0u];
        o.y = lds[p2][2u * s2 + 1u];
        __builtin_nontemporal_store(o, out + (size_t)base * 6u + el);
    }
}

// ---------- Fallback: round-1 direct kernel (if ws too small) -------------
__global__ __launch_bounds__(kBlock) void direct_kernel(
    const float* __restrict__ x,
    const u64*   __restrict__ emb,
    u64*         __restrict__ out,
    ResArr res)
{
    unsigned tid = blockIdx.x * (unsigned)kBlock + threadIdx.x;  // n*12 + l
    unsigned n   = tid / (unsigned)kLevels;
    unsigned l   = tid - n * (unsigned)kLevels;
    float r = res.r[0];
#pragma unroll
    for (int i = 1; i < kLevels; ++i) r = (l == (unsigned)i) ? res.r[i] : r;
    float px = x[n * 3u], py = x[n * 3u + 1u], pz = x[n * 3u + 2u];
    unsigned x0 = (unsigned)floorf(px * r);
    unsigned y0 = (unsigned)floorf(py * r);
    unsigned z0 = (unsigned)floorf(pz * r);
    unsigned h  = (x0 ^ (y0 * 2654435761u) ^ (z0 * 805459861u)) & kHashMask;
    __builtin_nontemporal_store(emb[l * kHashSize + h], out + tid);
}

extern "C" void kernel_launch(void* const* d_in, const int* in_sizes, int n_in,
                              void* d_out, int out_size, void* d_ws, size_t ws_size,
                              hipStream_t stream) {
    const float* x   = (const float*)d_in[0];
    const u64*   emb = (const u64*)d_in[1];

    // Replicate the reference's float64 resolution computation exactly.
    ResArr res;
    const double growth = std::exp((std::log(512.0) - std::log(16.0)) / 11.0);
    for (int i = 0; i < kLevels; ++i)
        res.r[i] = (float)(int)(16.0 * std::pow(growth, (double)i));

    const size_t ws_needed = (size_t)kHiLevels * kPoints * sizeof(u64); // 151 MB

    if (ws_size >= ws_needed) {
        unsigned* idx = (unsigned*)d_out;   // d_out doubles as idx scratch
        hipLaunchKernelGGL(hash_kernel, dim3(kHashBlocks), dim3(kBlock), 0, stream,
                           x, idx, res);
        hipLaunchKernelGGL(gather_hi_kernel, dim3(kGBlocks), dim3(kBlock), 0, stream,
                           idx, emb, (u64*)d_ws);
        hipLaunchKernelGGL(assemble_kernel, dim3(kPoints / kBlock), dim3(kBlock), 0, stream,
                           x, emb, (const u64*)d_ws, (u64x2*)d_out, res);
    } else {
        const int total = kPoints * kLevels;
        hipLaunchKernelGGL(direct_kernel, dim3(total / kBlock), dim3(kBlock), 0, stream,
                           x, emb, (u64*)d_out, res);
    }
}